// Round 1
// baseline (209.880 us; speedup 1.0000x reference)
//
#include <hip/hip_runtime.h>

#define NUM_DEM 2
#define VOCAB 10000
#define EMB 128
#define NROWS 16384
#define ROWLEN (NUM_DEM + VOCAB)      // 10002
#define KSTEPS 313                    // ceil(10000/32)
#define PCOLS 132                     // partial row stride: 128 pooled + 1 count + pad
#define BPACK_USHORTS (KSTEPS * 4096) // 4096 bf16 per K-step tile
#define BPACK_BYTES (BPACK_USHORTS * 2)

typedef float f32x4 __attribute__((ext_vector_type(4)));
typedef __bf16 bf16x8 __attribute__((ext_vector_type(8)));
typedef short s16x8 __attribute__((ext_vector_type(8)));

union Frag {
    s16x8 s;
    bf16x8 b;
    unsigned int u[4];
    unsigned short h[8];
};

__device__ __forceinline__ unsigned short f2bf_rtne(float f) {
    unsigned int u = __float_as_uint(f);
    u += 0x7FFFu + ((u >> 16) & 1u);
    return (unsigned short)(u >> 16);
}

// ---------------- kernel 0: pack embed (fp32 -> bf16 MFMA-B fragment order) ---------
// Bpack[((t*8 + c)*64 + l)*8 + j] = bf16(embed[t*32 + (l>>4)*8 + j][c*16 + (l&15)])
__global__ void pack_embed_k(const float* __restrict__ embed,
                             unsigned short* __restrict__ bp) {
    int id = blockIdx.x * blockDim.x + threadIdx.x;
    if (id >= KSTEPS * 8 * 64) return;
    int l = id & 63;
    int c = (id >> 6) & 7;
    int t = id >> 9;
    int kbase = t * 32 + ((l >> 4) * 8);
    int n = c * 16 + (l & 15);
    unsigned short v[8];
#pragma unroll
    for (int j = 0; j < 8; ++j) {
        int k = kbase + j;
        float f = (k < VOCAB) ? embed[(size_t)k * EMB + n] : 0.0f;
        v[j] = f2bf_rtne(f);
    }
    uint4 w;
    w.x = (unsigned int)v[0] | ((unsigned int)v[1] << 16);
    w.y = (unsigned int)v[2] | ((unsigned int)v[3] << 16);
    w.z = (unsigned int)v[4] | ((unsigned int)v[5] << 16);
    w.w = (unsigned int)v[6] | ((unsigned int)v[7] << 16);
    *reinterpret_cast<uint4*>(bp + (size_t)id * 8) = w;
}

// ---------------- kernel 1: split-K masked-sum GEMM via MFMA ------------------------
typedef const __attribute__((address_space(1))) unsigned int* gas_u32p;
typedef __attribute__((address_space(3))) unsigned int* las_u32p;
#define GLOAD_LDS16(g, l)                                                              \
    __builtin_amdgcn_global_load_lds((gas_u32p)(g), (las_u32p)(l), 16, 0, 0)

__global__ __launch_bounds__(256, 4) void main_gemm_k(
    const float* __restrict__ src, const unsigned short* __restrict__ bp,
    float* __restrict__ part, int nch) {
    __shared__ alignas(16) unsigned short ldsB[4096];  // 8 KB: one K-step B tile

    const int tid = threadIdx.x;
    const int lane = tid & 63;
    const int wid = tid >> 6;
    const int rb = blockIdx.x & 255;  // row block: 64 rows
    const int ch = blockIdx.x >> 8;   // K chunk
    const int t0 = (KSTEPS * ch) / nch;
    const int t1 = (KSTEPS * (ch + 1)) / nch;

    const int rowbase = rb * 64 + wid * 16;
    const int arow = rowbase + (lane & 15);
    const int kgrp8 = (lane >> 4) * 8;
    const float* asrc = src + (size_t)arow * ROWLEN + NUM_DEM + kgrp8;

    f32x4 pacc[8];
#pragma unroll
    for (int f = 0; f < 8; ++f) pacc[f] = (f32x4){0.f, 0.f, 0.f, 0.f};
    f32x4 cacc = (f32x4){0.f, 0.f, 0.f, 0.f};

    Frag onesf;  // B fragment with col 0 == 1.0 (for row counts), others 0
    {
        unsigned short o = ((lane & 15) == 0) ? (unsigned short)0x3F80 : (unsigned short)0;
        unsigned int ow = (unsigned int)o | ((unsigned int)o << 16);
        onesf.u[0] = ow; onesf.u[1] = ow; onesf.u[2] = ow; onesf.u[3] = ow;
    }

    for (int t = t0; t < t1; ++t) {
        // stage B tile (8 KB) into LDS: each thread 2 x 16B, linear layout
        const unsigned short* gB = bp + (size_t)t * 4096;
        GLOAD_LDS16(gB + wid * 1024 + lane * 8, ldsB + wid * 1024 + lane * 8);
        GLOAD_LDS16(gB + wid * 1024 + 512 + lane * 8, ldsB + wid * 1024 + 512 + lane * 8);

        // A: 8 consecutive fp32 (values are exactly 0.0/1.0)
        float4 a0, a1;
        int kb = t * 32 + kgrp8;
        if (kb + 8 <= VOCAB) {  // 10000 % 8 == 0, so group is all-valid or all-invalid
            const float* ap = asrc + (size_t)t * 32;
            a0 = *reinterpret_cast<const float4*>(ap);
            a1 = *reinterpret_cast<const float4*>(ap + 4);
        } else {
            a0 = make_float4(0.f, 0.f, 0.f, 0.f);
            a1 = a0;
        }

        __syncthreads();  // B tile resident, A regs ready

        Frag af;  // truncation fp32->bf16 is exact for 0.0/1.0
        af.u[0] = __builtin_amdgcn_perm(__float_as_uint(a0.y), __float_as_uint(a0.x), 0x07060302u);
        af.u[1] = __builtin_amdgcn_perm(__float_as_uint(a0.w), __float_as_uint(a0.z), 0x07060302u);
        af.u[2] = __builtin_amdgcn_perm(__float_as_uint(a1.y), __float_as_uint(a1.x), 0x07060302u);
        af.u[3] = __builtin_amdgcn_perm(__float_as_uint(a1.w), __float_as_uint(a1.z), 0x07060302u);

#pragma unroll
        for (int f = 0; f < 8; ++f) {
            Frag bfr;
            bfr.s = *reinterpret_cast<const s16x8*>(ldsB + f * 512 + lane * 8);
            pacc[f] = __builtin_amdgcn_mfma_f32_16x16x32_bf16(af.b, bfr.b, pacc[f], 0, 0, 0);
        }
        cacc = __builtin_amdgcn_mfma_f32_16x16x32_bf16(af.b, onesf.b, cacc, 0, 0, 0);

        __syncthreads();  // protect LDS before next stage
    }

    // epilogue: C/D layout col = lane&15, row = (lane>>4)*4 + reg
    const int rlo = (lane >> 4) * 4;
    float* pch = part + (size_t)ch * NROWS * PCOLS;
#pragma unroll
    for (int f = 0; f < 8; ++f) {
#pragma unroll
        for (int r = 0; r < 4; ++r) {
            int row = rowbase + rlo + r;
            pch[(size_t)row * PCOLS + f * 16 + (lane & 15)] = pacc[f][r];
        }
    }
    if ((lane & 15) == 0) {
#pragma unroll
        for (int r = 0; r < 4; ++r) {
            int row = rowbase + rlo + r;
            pch[(size_t)row * PCOLS + 128] = cacc[r];
        }
    }
}

// ---------------- kernel 2: reduce partials + MLP ----------------------------------
__global__ __launch_bounds__(256) void mlp_k(const float* __restrict__ part,
                                             const float* __restrict__ src,
                                             const float* __restrict__ W1,
                                             const float* __restrict__ b1,
                                             const float* __restrict__ W2,
                                             const float* __restrict__ b2,
                                             float* __restrict__ out, int nch) {
    __shared__ float xls[16][131];  // [dem(2), pooled(128)] per row
    __shared__ float hls[16][16];
    __shared__ float cnt[16];
    const int tid = threadIdx.x;
    const int rb = blockIdx.x * 16;

    if (tid < 16) {
        float s = 0.f;
        for (int c = 0; c < nch; ++c)
            s += part[((size_t)c * NROWS + rb + tid) * PCOLS + 128];
        cnt[tid] = s;
    }
    if (tid >= 16 && tid < 48) {
        int r = (tid - 16) >> 1, d = (tid - 16) & 1;
        xls[r][d] = src[(size_t)(rb + r) * ROWLEN + d];
    }
    __syncthreads();

    for (int idx = tid; idx < 16 * 128; idx += 256) {
        int r = idx >> 7, col = idx & 127;
        float s = 0.f;
        for (int c = 0; c < nch; ++c)
            s += part[((size_t)c * NROWS + rb + r) * PCOLS + col];
        xls[r][NUM_DEM + col] = s / cnt[r];
    }
    __syncthreads();

    {
        int r = tid >> 4, u = tid & 15;
        float acc = b1[u];
        for (int i = 0; i < NUM_DEM + EMB; ++i) acc += xls[r][i] * W1[i * 16 + u];
        hls[r][u] = tanhf(acc);
    }
    __syncthreads();

    if (tid < 32) {
        int r = tid >> 1, o = tid & 1;
        float acc = b2[o];
#pragma unroll
        for (int u = 0; u < 16; ++u) acc += hls[r][u] * W2[u * 2 + o];
        out[(size_t)(rb + r) * 2 + o] = acc;
    }
}

// ---------------- launch ------------------------------------------------------------
extern "C" void kernel_launch(void* const* d_in, const int* in_sizes, int n_in,
                              void* d_out, int out_size, void* d_ws, size_t ws_size,
                              hipStream_t stream) {
    const float* src = (const float*)d_in[0];
    const float* embed = (const float*)d_in[1];
    const float* W1 = (const float*)d_in[2];
    const float* b1 = (const float*)d_in[3];
    const float* W2 = (const float*)d_in[4];
    const float* b2 = (const float*)d_in[5];
    float* out = (float*)d_out;

    unsigned short* bpack = (unsigned short*)d_ws;
    float* part = (float*)((char*)d_ws + BPACK_BYTES);

    const size_t part1 = (size_t)NROWS * PCOLS * sizeof(float);
    int nch = 4;
    while (nch > 1 && BPACK_BYTES + part1 * (size_t)nch > ws_size) nch >>= 1;

    hipLaunchKernelGGL(pack_embed_k, dim3((KSTEPS * 8 * 64 + 255) / 256), dim3(256), 0,
                       stream, embed, bpack);
    hipLaunchKernelGGL(main_gemm_k, dim3(256 * nch), dim3(256), 0, stream, src, bpack,
                       part, nch);
    hipLaunchKernelGGL(mlp_k, dim3(NROWS / 16), dim3(256), 0, stream, part, src, W1, b1,
                       W2, b2, out, nch);
}